// Round 3
// baseline (283.121 us; speedup 1.0000x reference)
//
#include <hip/hip_runtime.h>
#include <hip/hip_bf16.h>

#define NN 50000
#define EE 800000
#define NEG 0.2f

using u32 = unsigned int;

// ---- K0: tiny precompute: Wtilde[16][4], cvec[64] (with b_gat@W_c folded in) ----
__global__ void k_pre(const float* __restrict__ W_edge, const float* __restrict__ att_edge,
                      const float* __restrict__ W_c, const float* __restrict__ b_c,
                      const float* __restrict__ ns, const float* __restrict__ b_gat,
                      float* __restrict__ Wt, float* __restrict__ cvec){
  int t = threadIdx.x;
  if (t < 64){
    int d = t >> 2, h = t & 3;
    float s = 0.f;
    for (int c = 0; c < 64; c++) s += W_edge[d*256 + h*64 + c] * att_edge[h*64 + c];
    Wt[d*4 + h] = s;
  } else if (t < 128){
    int j = t - 64;
    float s = b_c[j];
    for (int d = 0; d < 16; d++) s += ns[d >> 1] * W_c[(64 + d)*64 + j];
    for (int c = 0; c < 64; c++) s += b_gat[c] * W_c[c*64 + j];
    cvec[j] = s;
  }
}

// ---- K0b: av[128][8] = W_gat folded with att_src/att_dst ----
__global__ __launch_bounds__(1024) void k_pre_av(const float* __restrict__ Wg,
        const float* __restrict__ att_src, const float* __restrict__ att_dst,
        float* __restrict__ av){
  int tid = threadIdx.x;          // 1024 threads: k = tid>>3, o = tid&7
  int k = tid >> 3, o = tid & 7;
  int h = o & 3;
  const float* att = (o < 4) ? att_src : att_dst;
  float s = 0.f;
  for (int c = 0; c < 64; c++) s += Wg[k*256 + h*64 + c] * att[h*64 + c];
  av[k*8 + o] = s;                // o<4: src head o ; o>=4: dst head o-4
}

// ---- K0c: Wz[128][256] = W_gat @ blockdiag(W_c[0:64]) ----
__global__ __launch_bounds__(256) void k_pre_wz(const float* __restrict__ Wg,
        const float* __restrict__ W_c, float* __restrict__ Wz){
  __shared__ float sWg[256];
  __shared__ float sWc[64*64];
  int tid = threadIdx.x, k = blockIdx.x;
  sWg[tid] = Wg[k*256 + tid];
  for (int i = tid; i < 4096; i += 256) sWc[i] = W_c[i];
  __syncthreads();
  int h = tid >> 6, j = tid & 63;
  float s = 0.f;
  #pragma unroll 8
  for (int c = 0; c < 64; c++) s += sWg[h*64 + c] * sWc[c*64 + j];
  Wz[k*256 + tid] = s;
}

// ---- K1: zs = x @ Wz (fp32 compute, bf16 store) ----
#define BM 64
#define BK 16
__global__ __launch_bounds__(256) void k_gemm(const float* __restrict__ x,
                                              const float* __restrict__ Wz,
                                              __hip_bfloat16* __restrict__ zs){
  __shared__ float As[BK][BM];
  __shared__ float Bs[BK*256];
  int tid = threadIdx.x;
  int n0 = blockIdx.x * BM;
  int tc = tid & 31, tr = tid >> 5;
  float acc[8][8];
  #pragma unroll
  for (int i = 0; i < 8; i++)
    #pragma unroll
    for (int j = 0; j < 8; j++) acc[i][j] = 0.f;

  for (int k0 = 0; k0 < 128; k0 += BK){
    {
      int r = tid >> 2, kq = (tid & 3) * 4;
      int n = n0 + r; if (n >= NN) n = NN - 1;
      float4 v = *(const float4*)(x + (size_t)n*128 + k0 + kq);
      As[kq+0][r] = v.x; As[kq+1][r] = v.y; As[kq+2][r] = v.z; As[kq+3][r] = v.w;
    }
    #pragma unroll
    for (int i = 0; i < 4; i++){
      int f4 = i*256 + tid;
      *(float4*)&Bs[f4*4] = *(const float4*)(Wz + (size_t)k0*256 + f4*4);
    }
    __syncthreads();
    #pragma unroll
    for (int kk = 0; kk < BK; kk++){
      float a[8], b[8];
      float4 a0 = *(float4*)&As[kk][tr*8];
      float4 a1 = *(float4*)&As[kk][tr*8 + 4];
      float4 b0 = *(float4*)&Bs[kk*256 + tc*8];
      float4 b1 = *(float4*)&Bs[kk*256 + tc*8 + 4];
      a[0]=a0.x;a[1]=a0.y;a[2]=a0.z;a[3]=a0.w;a[4]=a1.x;a[5]=a1.y;a[6]=a1.z;a[7]=a1.w;
      b[0]=b0.x;b[1]=b0.y;b[2]=b0.z;b[3]=b0.w;b[4]=b1.x;b[5]=b1.y;b[6]=b1.z;b[7]=b1.w;
      #pragma unroll
      for (int i = 0; i < 8; i++)
        #pragma unroll
        for (int j = 0; j < 8; j++) acc[i][j] += a[i]*b[j];
    }
    __syncthreads();
  }
  #pragma unroll
  for (int i = 0; i < 8; i++){
    int n = n0 + tr*8 + i;
    if (n < NN){
      alignas(16) __hip_bfloat16 tmp[8];
      #pragma unroll
      for (int j = 0; j < 8; j++) tmp[j] = __float2bfloat16(acc[i][j]);
      *(uint4*)(zs + (size_t)n*256 + tc*8) = *(uint4*)tmp;
    }
  }
}

// ---- K1b: a_src/a_dst = x @ av  (32 nodes per block, LDS-tiled) ----
__global__ __launch_bounds__(256) void k_adot(const float* __restrict__ x,
        const float* __restrict__ av, float* __restrict__ a_src, float* __restrict__ a_dst){
  __shared__ float sx[32*129];
  __shared__ float sav[1024];
  int tid = threadIdx.x;
  int n0 = blockIdx.x * 32;
  #pragma unroll
  for (int i = 0; i < 16; i++){
    int idx = i*256 + tid;
    int r = idx >> 7, c = idx & 127;
    int gn = n0 + r; if (gn >= NN) gn = NN - 1;
    sx[r*129 + c] = x[(size_t)gn*128 + c];
  }
  #pragma unroll
  for (int j = 0; j < 4; j++) sav[j*256 + tid] = av[j*256 + tid];
  __syncthreads();
  int nl = tid >> 3, o = tid & 7;
  int n = n0 + nl;
  float s = 0.f;
  #pragma unroll 8
  for (int k = 0; k < 128; k++) s += sx[nl*129 + k] * sav[k*8 + o];
  if (n < NN){
    if (o < 4) a_src[(size_t)n*4 + o] = s;
    else       a_dst[(size_t)n*4 + (o-4)] = s;
  }
}

// ---- K2a: degree histogram ----
__global__ __launch_bounds__(256) void k_deg(const int* __restrict__ dsts, u32* __restrict__ deg){
  int i = blockIdx.x*256 + threadIdx.x;
  if (i*4 >= EE) return;
  int4 d4 = *(const int4*)(dsts + (size_t)i*4);
  atomicAdd(&deg[d4.x], 1u);
  atomicAdd(&deg[d4.y], 1u);
  atomicAdd(&deg[d4.z], 1u);
  atomicAdd(&deg[d4.w], 1u);
}

// ---- K3a/K3b: two-level exclusive scan of deg -> offs ----
__global__ __launch_bounds__(1024) void k_scan1(const u32* __restrict__ deg,
                                                u32* __restrict__ offs, u32* __restrict__ bsum){
  __shared__ u32 sd[1024];
  int t = threadIdx.x;
  int i = blockIdx.x*1024 + t;
  u32 v = (i < NN) ? deg[i] : 0u;
  sd[t] = v; __syncthreads();
  for (int off = 1; off < 1024; off <<= 1){
    u32 u = (t >= off) ? sd[t-off] : 0u;
    __syncthreads();
    sd[t] += u;
    __syncthreads();
  }
  if (i < NN) offs[i] = sd[t] - v;
  if (t == 1023) bsum[blockIdx.x] = sd[1023];
}

__global__ __launch_bounds__(1024) void k_scan2(u32* __restrict__ offs, const u32* __restrict__ bsum){
  int b = blockIdx.x;
  u32 p = 0;
  for (int j = 0; j < b; j++) p += bsum[j];
  int i = b*1024 + threadIdx.x;
  if (i < NN) offs[i] += p;
  if (i == NN-1){
    u32 tot = p;
    for (int j = b; j < 49; j++) tot += bsum[j];
    offs[NN] = tot;
  }
}

// ---- K4: per-edge logits + leaky_relu, written DIRECTLY in CSR order ----
__global__ __launch_bounds__(256) void k_edge(const float* __restrict__ qraw,
        const float* __restrict__ eattr, const int* __restrict__ eidx,
        const float* __restrict__ Wq1, const float* __restrict__ bq1,
        const float* __restrict__ Wq2, const float* __restrict__ bq2,
        const float* __restrict__ Wt,
        const float* __restrict__ a_src, const float* __restrict__ a_dst,
        const u32* __restrict__ offs, u32* __restrict__ cnt,
        float* __restrict__ alpha_csr, u32* __restrict__ srcs_csr){
  __shared__ float sWq1[32], sbq1[8], sWq2[128], sbq2[16], sWt[64];
  int tid = threadIdx.x;
  if (tid < 32) sWq1[tid] = Wq1[tid];
  else if (tid < 40)  sbq1[tid-32]  = bq1[tid-32];
  else if (tid < 168) sWq2[tid-40]  = Wq2[tid-40];
  else if (tid < 184) sbq2[tid-168] = bq2[tid-168];
  else if (tid < 248) sWt[tid-184]  = Wt[tid-184];
  __syncthreads();
  int e = blockIdx.x*256 + tid;
  if (e >= EE) return;

  float4 qr = *(const float4*)(qraw + (size_t)e*4);
  float t1[8];
  #pragma unroll
  for (int j = 0; j < 8; j++){
    float s = sbq1[j] + qr.x*sWq1[j] + qr.y*sWq1[8+j] + qr.z*sWq1[16+j] + qr.w*sWq1[24+j];
    t1[j] = fmaxf(s, 0.f);
  }
  float ae[4] = {0.f,0.f,0.f,0.f};
  const float* ea = eattr + (size_t)e*16;
  #pragma unroll
  for (int d = 0; d < 16; d++){
    float q = sbq2[d];
    #pragma unroll
    for (int j = 0; j < 8; j++) q += t1[j]*sWq2[j*16 + d];
    float v = ea[d] + q;
    #pragma unroll
    for (int h = 0; h < 4; h++) ae[h] += v * sWt[d*4 + h];
  }
  int src = eidx[e], dst = eidx[EE + e];
  float4 as4 = *(const float4*)(a_src + (size_t)src*4);
  float4 ad4 = *(const float4*)(a_dst + (size_t)dst*4);
  float4 out;
  float* po = (float*)&out;
  float av4[4] = {as4.x + ad4.x + ae[0], as4.y + ad4.y + ae[1],
                  as4.z + ad4.z + ae[2], as4.w + ad4.w + ae[3]};
  #pragma unroll
  for (int hh = 0; hh < 4; hh++){
    float a = av4[hh];
    po[hh] = (a >= 0.f) ? a : NEG*a;
  }
  u32 pos = offs[dst] + atomicAdd(&cnt[dst], 1u);
  ((float4*)alpha_csr)[pos] = out;
  srcs_csr[pos] = (u32)src;
}

// ---- K5: per-node online-softmax aggregation over zs; no barrier, no epilogue GEMM ----
__global__ __launch_bounds__(256) void k_agg(const __hip_bfloat16* __restrict__ zs,
        const u32* __restrict__ srcs_csr, const u32* __restrict__ offs,
        const float* __restrict__ alpha_csr,
        const float* __restrict__ cvec, float* __restrict__ out){
  int tid = threadIdx.x;
  int w = tid >> 6, lane = tid & 63;
  int n = blockIdx.x*4 + w;       // grid = NN/4 exactly
  int h = lane >> 4;              // this lane's head (channels lane*4..lane*4+3)
  u32 p0 = offs[n], p1 = offs[n+1];
  float m = -INFINITY, d = 0.f;
  float a0 = 0.f, a1 = 0.f, a2 = 0.f, a3 = 0.f;
  for (u32 p = p0; p < p1; p++){
    u32 src = srcs_csr[p];
    float al = alpha_csr[(size_t)p*4 + h];
    uint2 rv = *(const uint2*)(zs + (size_t)src*256 + lane*4);  // 4 bf16
    float x0 = __uint_as_float(rv.x << 16);
    float x1 = __uint_as_float(rv.x & 0xffff0000u);
    float x2 = __uint_as_float(rv.y << 16);
    float x3 = __uint_as_float(rv.y & 0xffff0000u);
    float nm = fmaxf(m, al);
    float r  = __expf(m - nm);    // == 1.0 exactly when max unchanged
    float wg = __expf(al - nm);
    m = nm;
    a0 = a0*r + wg*x0;
    a1 = a1*r + wg*x1;
    a2 = a2*r + wg*x2;
    a3 = a3*r + wg*x3;
    d  = fmaf(d, r, wg);
  }
  float inv = (d > 0.f) ? 0.25f / d : 0.f;
  a0 *= inv; a1 *= inv; a2 *= inv; a3 *= inv;
  // head mean: sum over lanes {h*16+q}, h=0..3
  a0 += __shfl_xor(a0, 16); a1 += __shfl_xor(a1, 16);
  a2 += __shfl_xor(a2, 16); a3 += __shfl_xor(a3, 16);
  a0 += __shfl_xor(a0, 32); a1 += __shfl_xor(a1, 32);
  a2 += __shfl_xor(a2, 32); a3 += __shfl_xor(a3, 32);
  if (lane < 16){
    float4 cv = *(const float4*)(cvec + lane*4);
    float4 o4;
    o4.x = fmaxf(a0 + cv.x, 0.f);
    o4.y = fmaxf(a1 + cv.y, 0.f);
    o4.z = fmaxf(a2 + cv.z, 0.f);
    o4.w = fmaxf(a3 + cv.w, 0.f);
    *(float4*)(out + (size_t)n*64 + lane*4) = o4;
  }
}

extern "C" void kernel_launch(void* const* d_in, const int* in_sizes, int n_in,
                              void* d_out, int out_size, void* d_ws, size_t ws_size,
                              hipStream_t stream){
  const float* x       = (const float*)d_in[0];
  const int*   eidx    = (const int*)d_in[1];
  const float* eattr   = (const float*)d_in[2];
  const float* qraw    = (const float*)d_in[3];
  const float* ns      = (const float*)d_in[4];
  const float* Wg      = (const float*)d_in[5];
  const float* att_src = (const float*)d_in[6];
  const float* att_dst = (const float*)d_in[7];
  const float* W_edge  = (const float*)d_in[8];
  const float* att_edge= (const float*)d_in[9];
  const float* b_gat   = (const float*)d_in[10];
  const float* Wq1     = (const float*)d_in[11];
  const float* bq1     = (const float*)d_in[12];
  const float* Wq2     = (const float*)d_in[13];
  const float* bq2     = (const float*)d_in[14];
  const float* W_c     = (const float*)d_in[15];
  const float* b_c     = (const float*)d_in[16];
  float* out = (float*)d_out;

  char* ws = (char*)d_ws;
  __hip_bfloat16* zs = (__hip_bfloat16*)ws;            // 25,600,000 B
  float* a_src    = (float*)(ws + 25600000);           //    800,000 B
  float* a_dst    = (float*)(ws + 26400000);           //    800,000 B
  float* alpha_csr= (float*)(ws + 27200000);           // 12,800,000 B
  u32* srcs_csr   = (u32*)(ws + 40000000);             //  3,200,000 B
  u32* deg        = (u32*)(ws + 43200000);             //    200,000 B
  u32* offs       = (u32*)(ws + 43400000);             //    200,064 B
  u32* cnt        = (u32*)(ws + 43600064);             //    200,000 B
  u32* bsum       = (u32*)(ws + 43800064);             //        256 B
  float* Wt       = (float*)(ws + 43800320);           //        256 B
  float* cvec     = (float*)(ws + 43800576);           //        256 B
  float* Wz       = (float*)(ws + 43800832);           //    131,072 B
  float* av       = (float*)(ws + 43931904);           //      4,096 B

  hipMemsetAsync(deg, 0, 200000, stream);
  hipMemsetAsync(cnt, 0, 200000, stream);

  k_pre   <<<1,    128, 0, stream>>>(W_edge, att_edge, W_c, b_c, ns, b_gat, Wt, cvec);
  k_pre_av<<<1,   1024, 0, stream>>>(Wg, att_src, att_dst, av);
  k_pre_wz<<<128,  256, 0, stream>>>(Wg, W_c, Wz);
  k_deg   <<<782,  256, 0, stream>>>(eidx + EE, deg);
  k_adot  <<<1563, 256, 0, stream>>>(x, av, a_src, a_dst);
  k_gemm  <<<782,  256, 0, stream>>>(x, Wz, zs);
  k_scan1 <<<49,  1024, 0, stream>>>(deg, offs, bsum);
  k_scan2 <<<49,  1024, 0, stream>>>(offs, bsum);
  k_edge  <<<3125, 256, 0, stream>>>(qraw, eattr, eidx, Wq1, bq1, Wq2, bq2, Wt,
                                     a_src, a_dst, offs, cnt, alpha_csr, srcs_csr);
  k_agg   <<<12500,256, 0, stream>>>(zs, srcs_csr, offs, alpha_csr, cvec, out);
}

// Round 4
// 228.615 us; speedup vs baseline: 1.2384x; 1.2384x over previous
//
#include <hip/hip_runtime.h>
#include <hip/hip_bf16.h>

#define NN 50000
#define EE 800000
#define NEG 0.2f

using u32 = unsigned int;

// ---- K0: merged precompute ----
// blocks 0..127 : Wz[k][256] = W_gat row k folded with blockdiag(W_c[0:64])
// block 128     : Wt[16][4], cvec[64] (ns-pool @ W_c + b_gat @ W_c + b_c folded)
// block 129     : av[128][8] = W_gat folded with att_src/att_dst
__global__ __launch_bounds__(256) void k_pre_all(
        const float* __restrict__ Wg, const float* __restrict__ W_c,
        const float* __restrict__ W_edge, const float* __restrict__ att_edge,
        const float* __restrict__ b_c, const float* __restrict__ ns,
        const float* __restrict__ b_gat,
        const float* __restrict__ att_src, const float* __restrict__ att_dst,
        float* __restrict__ Wz, float* __restrict__ Wt,
        float* __restrict__ cvec, float* __restrict__ av){
  int bid = blockIdx.x, tid = threadIdx.x;
  if (bid < 128){
    __shared__ float sWg[256];
    __shared__ float sWc[64*64];
    sWg[tid] = Wg[bid*256 + tid];
    for (int i = tid; i < 4096; i += 256) sWc[i] = W_c[i];
    __syncthreads();
    int h = tid >> 6, j = tid & 63;
    float s = 0.f;
    #pragma unroll 8
    for (int c = 0; c < 64; c++) s += sWg[h*64 + c] * sWc[c*64 + j];
    Wz[bid*256 + tid] = s;
  } else if (bid == 128){
    if (tid < 64){
      int d = tid >> 2, h = tid & 3;
      float s = 0.f;
      for (int c = 0; c < 64; c++) s += W_edge[d*256 + h*64 + c] * att_edge[h*64 + c];
      Wt[d*4 + h] = s;
    } else if (tid < 128){
      int j = tid - 64;
      float s = b_c[j];
      for (int d = 0; d < 16; d++) s += ns[d >> 1] * W_c[(64 + d)*64 + j];
      for (int c = 0; c < 64; c++) s += b_gat[c] * W_c[c*64 + j];
      cvec[j] = s;
    }
  } else {
    for (int i = tid; i < 1024; i += 256){
      int k = i >> 3, o = i & 7, h = o & 3;
      const float* att = (o < 4) ? att_src : att_dst;
      float s = 0.f;
      for (int c = 0; c < 64; c++) s += Wg[k*256 + h*64 + c] * att[h*64 + c];
      av[i] = s;
    }
  }
}

// ---- K1: zs = x @ Wz (bf16 store) + fused deg histogram + fused a_src/a_dst ----
#define BM 64
#define BK 16
__global__ __launch_bounds__(256) void k_gemm(const float* __restrict__ x,
                                              const float* __restrict__ Wz,
                                              const float* __restrict__ av,
                                              const int* __restrict__ dsts,
                                              __hip_bfloat16* __restrict__ zs,
                                              float* __restrict__ a_src,
                                              float* __restrict__ a_dst,
                                              u32* __restrict__ deg){
  __shared__ float As[BK][BM];
  __shared__ float Bs[BK*256];
  __shared__ float sav[1024];
  int tid = threadIdx.x;
  int n0 = blockIdx.x * BM;

  // fused degree histogram: overlaps with the compute-bound GEMM below
  {
    int g = blockIdx.x*256 + tid;
    if (g < EE/4){
      int4 d4 = *(const int4*)(dsts + (size_t)g*4);
      atomicAdd(&deg[d4.x], 1u);
      atomicAdd(&deg[d4.y], 1u);
      atomicAdd(&deg[d4.z], 1u);
      atomicAdd(&deg[d4.w], 1u);
    }
  }
  for (int i = tid; i < 1024; i += 256) sav[i] = av[i];

  int tc = tid & 31, tr = tid >> 5;
  int r0 = tid >> 3, o = tid & 7;   // adot: rows r0, r0+32, output slot o
  float pa0 = 0.f, pa1 = 0.f;
  float acc[8][8];
  #pragma unroll
  for (int i = 0; i < 8; i++)
    #pragma unroll
    for (int j = 0; j < 8; j++) acc[i][j] = 0.f;

  for (int k0 = 0; k0 < 128; k0 += BK){
    {
      int r = tid >> 2, kq = (tid & 3) * 4;
      int n = n0 + r; if (n >= NN) n = NN - 1;
      float4 v = *(const float4*)(x + (size_t)n*128 + k0 + kq);
      As[kq+0][r] = v.x; As[kq+1][r] = v.y; As[kq+2][r] = v.z; As[kq+3][r] = v.w;
    }
    #pragma unroll
    for (int i = 0; i < 4; i++){
      int f4 = i*256 + tid;
      *(float4*)&Bs[f4*4] = *(const float4*)(Wz + (size_t)k0*256 + f4*4);
    }
    __syncthreads();
    #pragma unroll
    for (int kk = 0; kk < BK; kk++){
      float a[8], b[8];
      float4 a0 = *(float4*)&As[kk][tr*8];
      float4 a1 = *(float4*)&As[kk][tr*8 + 4];
      float4 b0 = *(float4*)&Bs[kk*256 + tc*8];
      float4 b1 = *(float4*)&Bs[kk*256 + tc*8 + 4];
      a[0]=a0.x;a[1]=a0.y;a[2]=a0.z;a[3]=a0.w;a[4]=a1.x;a[5]=a1.y;a[6]=a1.z;a[7]=a1.w;
      b[0]=b0.x;b[1]=b0.y;b[2]=b0.z;b[3]=b0.w;b[4]=b1.x;b[5]=b1.y;b[6]=b1.z;b[7]=b1.w;
      #pragma unroll
      for (int i = 0; i < 8; i++)
        #pragma unroll
        for (int j = 0; j < 8; j++) acc[i][j] += a[i]*b[j];
    }
    // fused a_src/a_dst partial dots from staged As
    #pragma unroll
    for (int kk = 0; kk < BK; kk++){
      float w = sav[(k0+kk)*8 + o];
      pa0 += As[kk][r0]      * w;
      pa1 += As[kk][r0 + 32] * w;
    }
    __syncthreads();
  }
  #pragma unroll
  for (int i = 0; i < 8; i++){
    int n = n0 + tr*8 + i;
    if (n < NN){
      alignas(16) __hip_bfloat16 tmp[8];
      #pragma unroll
      for (int j = 0; j < 8; j++) tmp[j] = __float2bfloat16(acc[i][j]);
      *(uint4*)(zs + (size_t)n*256 + tc*8) = *(uint4*)tmp;
    }
  }
  {
    int na = n0 + r0, nb = n0 + r0 + 32;
    if (o < 4){
      if (na < NN) a_src[(size_t)na*4 + o] = pa0;
      if (nb < NN) a_src[(size_t)nb*4 + o] = pa1;
    } else {
      if (na < NN) a_dst[(size_t)na*4 + (o-4)] = pa0;
      if (nb < NN) a_dst[(size_t)nb*4 + (o-4)] = pa1;
    }
  }
}

// ---- K3a/K3b: two-level exclusive scan of deg -> offs (+ cnt zeroing) ----
__global__ __launch_bounds__(1024) void k_scan1(const u32* __restrict__ deg,
                                                u32* __restrict__ offs, u32* __restrict__ bsum){
  __shared__ u32 sd[1024];
  int t = threadIdx.x;
  int i = blockIdx.x*1024 + t;
  u32 v = (i < NN) ? deg[i] : 0u;
  sd[t] = v; __syncthreads();
  for (int off = 1; off < 1024; off <<= 1){
    u32 u = (t >= off) ? sd[t-off] : 0u;
    __syncthreads();
    sd[t] += u;
    __syncthreads();
  }
  if (i < NN) offs[i] = sd[t] - v;
  if (t == 1023) bsum[blockIdx.x] = sd[1023];
}

__global__ __launch_bounds__(1024) void k_scan2(u32* __restrict__ offs, const u32* __restrict__ bsum,
                                                u32* __restrict__ cnt){
  int b = blockIdx.x;
  u32 p = 0;
  for (int j = 0; j < b; j++) p += bsum[j];
  int i = b*1024 + threadIdx.x;
  if (i < NN){ offs[i] += p; cnt[i] = 0u; }
  if (i == NN-1){
    u32 tot = p;
    for (int j = b; j < 49; j++) tot += bsum[j];
    offs[NN] = tot;
  }
}

// ---- K4: per-edge logits + leaky_relu, written DIRECTLY in CSR order ----
__global__ __launch_bounds__(256) void k_edge(const float* __restrict__ qraw,
        const float* __restrict__ eattr, const int* __restrict__ eidx,
        const float* __restrict__ Wq1, const float* __restrict__ bq1,
        const float* __restrict__ Wq2, const float* __restrict__ bq2,
        const float* __restrict__ Wt,
        const float* __restrict__ a_src, const float* __restrict__ a_dst,
        const u32* __restrict__ offs, u32* __restrict__ cnt,
        float* __restrict__ alpha_csr, u32* __restrict__ srcs_csr){
  __shared__ float sWq1[32], sbq1[8], sWq2[128], sbq2[16], sWt[64];
  int tid = threadIdx.x;
  if (tid < 32) sWq1[tid] = Wq1[tid];
  else if (tid < 40)  sbq1[tid-32]  = bq1[tid-32];
  else if (tid < 168) sWq2[tid-40]  = Wq2[tid-40];
  else if (tid < 184) sbq2[tid-168] = bq2[tid-168];
  else if (tid < 248) sWt[tid-184]  = Wt[tid-184];
  __syncthreads();
  int e = blockIdx.x*256 + tid;
  if (e >= EE) return;

  float4 qr = *(const float4*)(qraw + (size_t)e*4);
  float t1[8];
  #pragma unroll
  for (int j = 0; j < 8; j++){
    float s = sbq1[j] + qr.x*sWq1[j] + qr.y*sWq1[8+j] + qr.z*sWq1[16+j] + qr.w*sWq1[24+j];
    t1[j] = fmaxf(s, 0.f);
  }
  float ae[4] = {0.f,0.f,0.f,0.f};
  const float* ea = eattr + (size_t)e*16;
  #pragma unroll
  for (int d = 0; d < 16; d++){
    float q = sbq2[d];
    #pragma unroll
    for (int j = 0; j < 8; j++) q += t1[j]*sWq2[j*16 + d];
    float v = ea[d] + q;
    #pragma unroll
    for (int h = 0; h < 4; h++) ae[h] += v * sWt[d*4 + h];
  }
  int src = eidx[e], dst = eidx[EE + e];
  float4 as4 = *(const float4*)(a_src + (size_t)src*4);
  float4 ad4 = *(const float4*)(a_dst + (size_t)dst*4);
  float4 out;
  float* po = (float*)&out;
  float av4[4] = {as4.x + ad4.x + ae[0], as4.y + ad4.y + ae[1],
                  as4.z + ad4.z + ae[2], as4.w + ad4.w + ae[3]};
  #pragma unroll
  for (int hh = 0; hh < 4; hh++){
    float a = av4[hh];
    po[hh] = (a >= 0.f) ? a : NEG*a;
  }
  u32 pos = offs[dst] + atomicAdd(&cnt[dst], 1u);
  ((float4*)alpha_csr)[pos] = out;
  srcs_csr[pos] = (u32)src;
}

// ---- K5: per-node aggregation, NO max subtraction (logits bounded), 4x unroll ----
__global__ __launch_bounds__(256) void k_agg(const __hip_bfloat16* __restrict__ zs,
        const u32* __restrict__ srcs_csr, const u32* __restrict__ offs,
        const float* __restrict__ alpha_csr,
        const float* __restrict__ cvec, float* __restrict__ out){
  int tid = threadIdx.x;
  int w = tid >> 6, lane = tid & 63;
  int n = blockIdx.x*4 + w;       // grid = NN/4 exactly
  int h = lane >> 4;              // this lane's head (channels lane*4..lane*4+3)
  u32 p0 = offs[n], p1 = offs[n+1];
  float d = 0.f;
  float a0 = 0.f, a1 = 0.f, a2 = 0.f, a3 = 0.f;
  u32 p = p0;
  for (; p + 4 <= p1; p += 4){
    u32 s0 = srcs_csr[p+0], s1 = srcs_csr[p+1], s2 = srcs_csr[p+2], s3 = srcs_csr[p+3];
    float al0 = alpha_csr[(size_t)(p+0)*4 + h];
    float al1 = alpha_csr[(size_t)(p+1)*4 + h];
    float al2 = alpha_csr[(size_t)(p+2)*4 + h];
    float al3 = alpha_csr[(size_t)(p+3)*4 + h];
    uint2 v0 = *(const uint2*)(zs + (size_t)s0*256 + lane*4);
    uint2 v1 = *(const uint2*)(zs + (size_t)s1*256 + lane*4);
    uint2 v2 = *(const uint2*)(zs + (size_t)s2*256 + lane*4);
    uint2 v3 = *(const uint2*)(zs + (size_t)s3*256 + lane*4);
    float w0 = __expf(al0), w1 = __expf(al1), w2 = __expf(al2), w3 = __expf(al3);
    a0 += w0*__uint_as_float(v0.x << 16)        + w1*__uint_as_float(v1.x << 16)
        + w2*__uint_as_float(v2.x << 16)        + w3*__uint_as_float(v3.x << 16);
    a1 += w0*__uint_as_float(v0.x & 0xffff0000u)+ w1*__uint_as_float(v1.x & 0xffff0000u)
        + w2*__uint_as_float(v2.x & 0xffff0000u)+ w3*__uint_as_float(v3.x & 0xffff0000u);
    a2 += w0*__uint_as_float(v0.y << 16)        + w1*__uint_as_float(v1.y << 16)
        + w2*__uint_as_float(v2.y << 16)        + w3*__uint_as_float(v3.y << 16);
    a3 += w0*__uint_as_float(v0.y & 0xffff0000u)+ w1*__uint_as_float(v1.y & 0xffff0000u)
        + w2*__uint_as_float(v2.y & 0xffff0000u)+ w3*__uint_as_float(v3.y & 0xffff0000u);
    d  += (w0 + w1) + (w2 + w3);
  }
  for (; p < p1; p++){
    u32 s0 = srcs_csr[p];
    float al = alpha_csr[(size_t)p*4 + h];
    uint2 v0 = *(const uint2*)(zs + (size_t)s0*256 + lane*4);
    float w0 = __expf(al);
    a0 += w0*__uint_as_float(v0.x << 16);
    a1 += w0*__uint_as_float(v0.x & 0xffff0000u);
    a2 += w0*__uint_as_float(v0.y << 16);
    a3 += w0*__uint_as_float(v0.y & 0xffff0000u);
    d  += w0;
  }
  float inv = (d > 0.f) ? 0.25f / d : 0.f;
  a0 *= inv; a1 *= inv; a2 *= inv; a3 *= inv;
  // head mean: sum over the 4 head-groups of 16 lanes
  a0 += __shfl_xor(a0, 16); a1 += __shfl_xor(a1, 16);
  a2 += __shfl_xor(a2, 16); a3 += __shfl_xor(a3, 16);
  a0 += __shfl_xor(a0, 32); a1 += __shfl_xor(a1, 32);
  a2 += __shfl_xor(a2, 32); a3 += __shfl_xor(a3, 32);
  if (lane < 16){
    float4 cv = *(const float4*)(cvec + lane*4);
    float4 o4;
    o4.x = fmaxf(a0 + cv.x, 0.f);
    o4.y = fmaxf(a1 + cv.y, 0.f);
    o4.z = fmaxf(a2 + cv.z, 0.f);
    o4.w = fmaxf(a3 + cv.w, 0.f);
    *(float4*)(out + (size_t)n*64 + lane*4) = o4;
  }
}

extern "C" void kernel_launch(void* const* d_in, const int* in_sizes, int n_in,
                              void* d_out, int out_size, void* d_ws, size_t ws_size,
                              hipStream_t stream){
  const float* x       = (const float*)d_in[0];
  const int*   eidx    = (const int*)d_in[1];
  const float* eattr   = (const float*)d_in[2];
  const float* qraw    = (const float*)d_in[3];
  const float* ns      = (const float*)d_in[4];
  const float* Wg      = (const float*)d_in[5];
  const float* att_src = (const float*)d_in[6];
  const float* att_dst = (const float*)d_in[7];
  const float* W_edge  = (const float*)d_in[8];
  const float* att_edge= (const float*)d_in[9];
  const float* b_gat   = (const float*)d_in[10];
  const float* Wq1     = (const float*)d_in[11];
  const float* bq1     = (const float*)d_in[12];
  const float* Wq2     = (const float*)d_in[13];
  const float* bq2     = (const float*)d_in[14];
  const float* W_c     = (const float*)d_in[15];
  const float* b_c     = (const float*)d_in[16];
  float* out = (float*)d_out;

  char* ws = (char*)d_ws;
  __hip_bfloat16* zs = (__hip_bfloat16*)ws;            // 25,600,000 B
  float* a_src    = (float*)(ws + 25600000);           //    800,000 B
  float* a_dst    = (float*)(ws + 26400000);           //    800,000 B
  float* alpha_csr= (float*)(ws + 27200000);           // 12,800,000 B
  u32* srcs_csr   = (u32*)(ws + 40000000);             //  3,200,000 B
  u32* deg        = (u32*)(ws + 43200000);             //    200,000 B
  u32* offs       = (u32*)(ws + 43400000);             //    200,064 B
  u32* cnt        = (u32*)(ws + 43600064);             //    200,000 B
  u32* bsum       = (u32*)(ws + 43800064);             //        256 B
  float* Wt       = (float*)(ws + 43800320);           //        256 B
  float* cvec     = (float*)(ws + 43800576);           //        256 B
  float* Wz       = (float*)(ws + 43800832);           //    131,072 B
  float* av       = (float*)(ws + 43931904);           //      4,096 B

  hipMemsetAsync(deg, 0, 200000, stream);

  k_pre_all<<<130,  256, 0, stream>>>(Wg, W_c, W_edge, att_edge, b_c, ns, b_gat,
                                      att_src, att_dst, Wz, Wt, cvec, av);
  k_gemm   <<<782,  256, 0, stream>>>(x, Wz, av, eidx + EE, zs, a_src, a_dst, deg);
  k_scan1  <<<49,  1024, 0, stream>>>(deg, offs, bsum);
  k_scan2  <<<49,  1024, 0, stream>>>(offs, bsum, cnt);
  k_edge   <<<3125, 256, 0, stream>>>(qraw, eattr, eidx, Wq1, bq1, Wq2, bq2, Wt,
                                      a_src, a_dst, offs, cnt, alpha_csr, srcs_csr);
  k_agg    <<<12500,256, 0, stream>>>(zs, srcs_csr, offs, alpha_csr, cvec, out);
}